// Round 2
// baseline (564.291 us; speedup 1.0000x reference)
//
#include <hip/hip_runtime.h>
#include <hip/hip_bf16.h>
#include <math.h>

#define GH 721
#define GW 1440
#define C_IN 78
#define NNODES 5882
#define KNEIGH 128
#define M_TOTAL (NNODES * KNEIGH)   // 752896
#define TM 64
#define NBLOCKS (M_TOTAL / TM)      // 11764

typedef __attribute__((ext_vector_type(8))) short bf16x8;
typedef __attribute__((ext_vector_type(4))) float f32x4;

__device__ __forceinline__ unsigned short f2bf(float x) {
    __hip_bfloat16 b = __float2bfloat16(x);
    union { __hip_bfloat16 h; unsigned short u; } cv; cv.h = b; return cv.u;
}

// ---------------- prep kernel ----------------
// bp1: [3][4][256][8] bf16 = W1 * inv_std (rows >=82 zero; constants folded into b1p)
// bp2: [8][4][256][8] bf16 = W2
// latT: [721][2] raw (sin,cos) lat;  lonT: [1440][2] raw (sin,cos) lon
// b1p: [256] f32 = b1 - sum_k mean[k]*W1'[k,c] + 0.5*W1'[82,c]
__global__ void prep_kernel(const float* __restrict__ W1, const float* __restrict__ W2,
                            const float* __restrict__ means, const float* __restrict__ stds,
                            const float* __restrict__ b1,
                            unsigned short* __restrict__ bp1, unsigned short* __restrict__ bp2,
                            float* __restrict__ latT, float* __restrict__ lonT,
                            float* __restrict__ b1p)
{
    const int NB1 = 3 * 4 * 256 * 8;   // 24576
    const int NB2 = 8 * 4 * 256 * 8;   // 65536
    const int NTOT = NB1 + NB2 + GH + GW + 256;
    for (int e = blockIdx.x * blockDim.x + threadIdx.x; e < NTOT;
         e += gridDim.x * blockDim.x) {
        if (e < NB1) {
            int j = e & 7, c = (e >> 3) & 255, o = (e >> 11) & 3, s = e >> 13;
            int k = s * 32 + o * 8 + j;
            float v = 0.f;
            if (k < 82) v = W1[k * 256 + c] / (stds[k] + 1e-7f);
            bp1[e] = f2bf(v);
        } else if (e < NB1 + NB2) {
            int t = e - NB1;
            int j = t & 7, c = (t >> 3) & 255, o = (t >> 11) & 3, s = t >> 13;
            int k = s * 32 + o * 8 + j;
            bp2[t] = f2bf(W2[k * 256 + c]);
        } else if (e < NB1 + NB2 + GH) {
            int h = e - NB1 - NB2;
            float r = (-90.f + 0.25f * (float)h) * 0.017453292519943295f;
            latT[2 * h]     = sinf(r);
            latT[2 * h + 1] = cosf(r);
        } else if (e < NB1 + NB2 + GH + GW) {
            int w = e - NB1 - NB2 - GH;
            float r = ((float)w * (360.f / 1439.f)) * 0.017453292519943295f;
            lonT[2 * w]     = sinf(r);
            lonT[2 * w + 1] = cosf(r);
        } else {
            int c = e - NB1 - NB2 - GH - GW;
            float acc = b1[c];
            #pragma unroll 1
            for (int k = 0; k < 86; ++k) {
                float inv = 1.f / (stds[k] + 1e-7f);
                float w = W1[k * 256 + c] * inv;
                acc -= means[k] * w;
                if (k == 82) acc += 0.5f * w;   // day-of-year channel, raw value 0.5
            }
            b1p[c] = acc;
        }
    }
}

// ---------------- fused kernel ----------------
__global__ __launch_bounds__(256, 4)
void fused_kernel(const float* __restrict__ var_grid, const int* __restrict__ idxs,
                  const unsigned short* __restrict__ bp1, const unsigned short* __restrict__ bp2,
                  const float* __restrict__ latT, const float* __restrict__ lonT,
                  const float* __restrict__ b1p, const float* __restrict__ lnS,
                  const float* __restrict__ lnO, const float* __restrict__ b2,
                  float* __restrict__ out)
{
    __shared__ unsigned short h_lds[TM * 256];     // 32 KiB; x tile aliases the front
    __shared__ float red[2][4][TM];                // 2 KiB LN partials
    unsigned short (*x_lds)[104] = (unsigned short (*)[104])h_lds;  // 64*104*2 = 13312 B

    const int tid  = threadIdx.x;
    const int lane = tid & 63;
    const int wave = tid >> 6;       // 0..3
    const int l15  = lane & 15;
    const int lg   = lane >> 4;      // 0..3
    const int wbase = wave * 64;
    const long block0 = (long)blockIdx.x * TM;

    // ---- gather: raw values -> bf16 LDS tile (norm folded into W1/b1) ----
    {
        const int row = tid >> 2, p = tid & 3;     // 4 lanes per row
        const int idx = idxs[block0 + row];
        const int hh = idx / GW;
        const int ww = idx - hh * GW;
        const float* src = var_grid + (long)idx * C_IN;
        unsigned int* xrow = (unsigned int*)&x_lds[row][0];
        #pragma unroll
        for (int t = 0; t < 12; ++t) {
            const int q = p + 4 * t;               // q covers channels 2q, 2q+1
            float v0, v1;
            if (q < 39) {
                float2 t2 = *(const float2*)(src + 2 * q);
                v0 = t2.x; v1 = t2.y;
            } else if (q == 39) { v0 = latT[2 * hh]; v1 = latT[2 * hh + 1]; }
            else if (q == 40)   { v0 = lonT[2 * ww]; v1 = lonT[2 * ww + 1]; }
            else                { v0 = 0.f; v1 = 0.f; }   // ch 82..95: folded / pad
            xrow[q] = ((unsigned int)f2bf(v1) << 16) | (unsigned int)f2bf(v0);
        }
    }

    // per-column params (overlap with gather latency)
    float b1v[4], lsv[4], lov[4], b2v[4];
    #pragma unroll
    for (int nf = 0; nf < 4; ++nf) {
        int col = wbase + nf * 16 + l15;
        b1v[nf] = b1p[col]; lsv[nf] = lnS[col]; lov[nf] = lnO[col]; b2v[nf] = b2[col];
    }
    __syncthreads();

    // ---- GEMM1: x[64x96] @ W1'[96x256] ----
    f32x4 acc[4][4];
    #pragma unroll
    for (int mf = 0; mf < 4; ++mf)
        #pragma unroll
        for (int nf = 0; nf < 4; ++nf) acc[mf][nf] = (f32x4){0.f, 0.f, 0.f, 0.f};

    #pragma unroll
    for (int s = 0; s < 3; ++s) {
        bf16x8 af[4], bw[4];
        #pragma unroll
        for (int mf = 0; mf < 4; ++mf)
            af[mf] = *(const bf16x8*)&x_lds[mf * 16 + l15][s * 32 + lg * 8];
        #pragma unroll
        for (int nf = 0; nf < 4; ++nf)
            bw[nf] = *(const bf16x8*)(bp1 + ((size_t)((s * 4 + lg) * 256) + wbase + nf * 16 + l15) * 8);
        #pragma unroll
        for (int mf = 0; mf < 4; ++mf)
            #pragma unroll
            for (int nf = 0; nf < 4; ++nf)
                acc[mf][nf] = __builtin_amdgcn_mfma_f32_16x16x32_bf16(af[mf], bw[nf], acc[mf][nf], 0, 0, 0);
    }

    // ---- bias + ReLU + LN partials ----
    float sm[4][4], sq[4][4];
    #pragma unroll
    for (int mf = 0; mf < 4; ++mf)
        #pragma unroll
        for (int i = 0; i < 4; ++i) { sm[mf][i] = 0.f; sq[mf][i] = 0.f; }

    #pragma unroll
    for (int mf = 0; mf < 4; ++mf)
        #pragma unroll
        for (int nf = 0; nf < 4; ++nf)
            #pragma unroll
            for (int i = 0; i < 4; ++i) {
                float v = fmaxf(acc[mf][nf][i] + b1v[nf], 0.f);
                acc[mf][nf][i] = v;
                sm[mf][i] += v;
                sq[mf][i] += v * v;
            }

    #pragma unroll
    for (int m = 1; m < 16; m <<= 1)
        #pragma unroll
        for (int mf = 0; mf < 4; ++mf)
            #pragma unroll
            for (int i = 0; i < 4; ++i) {
                sm[mf][i] += __shfl_xor(sm[mf][i], m, 64);
                sq[mf][i] += __shfl_xor(sq[mf][i], m, 64);
            }

    if (l15 == 0) {
        #pragma unroll
        for (int mf = 0; mf < 4; ++mf)
            #pragma unroll
            for (int i = 0; i < 4; ++i) {
                int row = mf * 16 + lg * 4 + i;
                red[0][wave][row] = sm[mf][i];
                red[1][wave][row] = sq[mf][i];
            }
    }
    __syncthreads();

    // ---- LN finish -> bf16 h_lds (swizzled) ----
    #pragma unroll
    for (int mf = 0; mf < 4; ++mf)
        #pragma unroll
        for (int i = 0; i < 4; ++i) {
            int row = mf * 16 + lg * 4 + i;
            float tot = red[0][0][row] + red[0][1][row] + red[0][2][row] + red[0][3][row];
            float tq  = red[1][0][row] + red[1][1][row] + red[1][2][row] + red[1][3][row];
            float mean = tot * (1.f / 256.f);
            float var  = tq * (1.f / 256.f) - mean * mean;
            float rs = rsqrtf(var + 1e-5f);
            #pragma unroll
            for (int nf = 0; nf < 4; ++nf) {
                float v = (acc[mf][nf][i] - mean) * rs * lsv[nf] + lov[nf];
                int col = wbase + nf * 16 + l15;
                unsigned off = (unsigned)(row * 512 + col * 2);
                off ^= (unsigned)((row & 7) << 4);
                *(unsigned short*)((char*)h_lds + off) = f2bf(v);
            }
        }
    __syncthreads();

    // ---- GEMM2: h[64x256] @ W2[256x256] ----
    #pragma unroll
    for (int mf = 0; mf < 4; ++mf)
        #pragma unroll
        for (int nf = 0; nf < 4; ++nf) acc[mf][nf] = (f32x4){0.f, 0.f, 0.f, 0.f};

    #pragma unroll
    for (int s = 0; s < 8; ++s) {
        bf16x8 af[4], bw[4];
        #pragma unroll
        for (int mf = 0; mf < 4; ++mf) {
            int row = mf * 16 + l15;
            unsigned off = (unsigned)(row * 512 + (s * 32 + lg * 8) * 2);
            off ^= (unsigned)((row & 7) << 4);
            af[mf] = *(const bf16x8*)((char*)h_lds + off);
        }
        #pragma unroll
        for (int nf = 0; nf < 4; ++nf)
            bw[nf] = *(const bf16x8*)(bp2 + ((size_t)((s * 4 + lg) * 256) + wbase + nf * 16 + l15) * 8);
        #pragma unroll
        for (int mf = 0; mf < 4; ++mf)
            #pragma unroll
            for (int nf = 0; nf < 4; ++nf)
                acc[mf][nf] = __builtin_amdgcn_mfma_f32_16x16x32_bf16(af[mf], bw[nf], acc[mf][nf], 0, 0, 0);
    }

    // ---- epilogue ----
    #pragma unroll
    for (int mf = 0; mf < 4; ++mf)
        #pragma unroll
        for (int i = 0; i < 4; ++i) {
            long row_g = block0 + mf * 16 + lg * 4 + i;
            float* po = out + row_g * 256 + wbase;
            #pragma unroll
            for (int nf = 0; nf < 4; ++nf)
                po[nf * 16 + l15] = acc[mf][nf][i] + b2v[nf];
        }
}

extern "C" void kernel_launch(void* const* d_in, const int* in_sizes, int n_in,
                              void* d_out, int out_size, void* d_ws, size_t ws_size,
                              hipStream_t stream) {
    const float* var_grid = (const float*)d_in[0];
    const int*   idxs     = (const int*)d_in[1];
    const float* means    = (const float*)d_in[2];
    const float* stds     = (const float*)d_in[3];
    const float* W1       = (const float*)d_in[4];
    const float* b1       = (const float*)d_in[5];
    const float* lnS      = (const float*)d_in[6];
    const float* lnO      = (const float*)d_in[7];
    const float* W2       = (const float*)d_in[8];
    const float* b2       = (const float*)d_in[9];
    float* out = (float*)d_out;

    char* ws = (char*)d_ws;
    unsigned short* bp1 = (unsigned short*)ws;               // 49152 B
    unsigned short* bp2 = (unsigned short*)(ws + 49152);     // 131072 B -> 180224
    float* latT = (float*)(ws + 180224);                     // 5768 B
    float* lonT = (float*)(ws + 186000);                     // 11520 B
    float* b1p  = (float*)(ws + 197520);                     // 1024 B  (end 198544)

    prep_kernel<<<362, 256, 0, stream>>>(W1, W2, means, stds, b1, bp1, bp2, latT, lonT, b1p);
    fused_kernel<<<NBLOCKS, 256, 0, stream>>>(var_grid, idxs, bp1, bp2, latT, lonT,
                                              b1p, lnS, lnO, b2, out);
}

// Round 3
// 557.414 us; speedup vs baseline: 1.0123x; 1.0123x over previous
//
#include <hip/hip_runtime.h>
#include <hip/hip_bf16.h>
#include <math.h>

#define GH 721
#define GW 1440
#define C_IN 78
#define NNODES 5882
#define KNEIGH 128
#define M_TOTAL (NNODES * KNEIGH)   // 752896
#define TM 64
#define NBLOCKS (M_TOTAL / TM)      // 11764

typedef __attribute__((ext_vector_type(8))) short bf16x8;
typedef __attribute__((ext_vector_type(4))) float f32x4;

__device__ __forceinline__ unsigned short f2bf(float x) {
    __hip_bfloat16 b = __float2bfloat16(x);
    union { __hip_bfloat16 h; unsigned short u; } cv; cv.h = b; return cv.u;
}

// ---------------- prep kernel ----------------
// bp1: [3][4][256][8] bf16 = W1 * inv_std (rows >=82 zero; constants folded into b1p)
// bp2: [8][4][256][8] bf16 = W2
// latT: [721][2] raw (sin,cos) lat;  lonT: [1440][2] raw (sin,cos) lon
// b1p: [256] f32 = b1 - sum_k mean[k]*W1'[k,c] + 0.5*W1'[82,c]
__global__ void prep_kernel(const float* __restrict__ W1, const float* __restrict__ W2,
                            const float* __restrict__ means, const float* __restrict__ stds,
                            const float* __restrict__ b1,
                            unsigned short* __restrict__ bp1, unsigned short* __restrict__ bp2,
                            float* __restrict__ latT, float* __restrict__ lonT,
                            float* __restrict__ b1p)
{
    const int NB1 = 3 * 4 * 256 * 8;   // 24576
    const int NB2 = 8 * 4 * 256 * 8;   // 65536
    const int NTOT = NB1 + NB2 + GH + GW + 256;
    for (int e = blockIdx.x * blockDim.x + threadIdx.x; e < NTOT;
         e += gridDim.x * blockDim.x) {
        if (e < NB1) {
            int j = e & 7, c = (e >> 3) & 255, o = (e >> 11) & 3, s = e >> 13;
            int k = s * 32 + o * 8 + j;
            float v = 0.f;
            if (k < 82) v = W1[k * 256 + c] / (stds[k] + 1e-7f);
            bp1[e] = f2bf(v);
        } else if (e < NB1 + NB2) {
            int t = e - NB1;
            int j = t & 7, c = (t >> 3) & 255, o = (t >> 11) & 3, s = t >> 13;
            int k = s * 32 + o * 8 + j;
            bp2[t] = f2bf(W2[k * 256 + c]);
        } else if (e < NB1 + NB2 + GH) {
            int h = e - NB1 - NB2;
            float r = (-90.f + 0.25f * (float)h) * 0.017453292519943295f;
            latT[2 * h]     = sinf(r);
            latT[2 * h + 1] = cosf(r);
        } else if (e < NB1 + NB2 + GH + GW) {
            int w = e - NB1 - NB2 - GH;
            float r = ((float)w * (360.f / 1439.f)) * 0.017453292519943295f;
            lonT[2 * w]     = sinf(r);
            lonT[2 * w + 1] = cosf(r);
        } else {
            int c = e - NB1 - NB2 - GH - GW;
            float acc = b1[c];
            #pragma unroll 1
            for (int k = 0; k < 86; ++k) {
                float inv = 1.f / (stds[k] + 1e-7f);
                float w = W1[k * 256 + c] * inv;
                acc -= means[k] * w;
                if (k == 82) acc += 0.5f * w;   // day-of-year channel, raw value 0.5
            }
            b1p[c] = acc;
        }
    }
}

// ---------------- fused kernel ----------------
__global__ __launch_bounds__(256, 4)
void fused_kernel(const float* __restrict__ var_grid, const int* __restrict__ idxs,
                  const unsigned short* __restrict__ bp1, const unsigned short* __restrict__ bp2,
                  const float* __restrict__ latT, const float* __restrict__ lonT,
                  const float* __restrict__ b1p, const float* __restrict__ lnS,
                  const float* __restrict__ lnO, const float* __restrict__ b2,
                  float* __restrict__ out)
{
    __shared__ unsigned short h_lds[TM * 256];     // 32 KiB; x tile aliases the front
    __shared__ float red[2][4][TM];                // 2 KiB LN partials
    unsigned short (*x_lds)[104] = (unsigned short (*)[104])h_lds;  // 64*104*2 = 13312 B

    const int tid  = threadIdx.x;
    const int lane = tid & 63;
    const int wave = tid >> 6;       // 0..3
    const int l15  = lane & 15;
    const int lg   = lane >> 4;      // 0..3
    const int wbase = wave * 64;
    const long block0 = (long)blockIdx.x * TM;

    // ---- gather: raw values -> bf16 LDS tile (norm folded into W1/b1) ----
    {
        const int row = tid >> 2, p = tid & 3;     // 4 lanes per row
        const int idx = idxs[block0 + row];
        const int hh = idx / GW;
        const int ww = idx - hh * GW;
        const float* src = var_grid + (long)idx * C_IN;
        unsigned int* xrow = (unsigned int*)&x_lds[row][0];
        #pragma unroll
        for (int t = 0; t < 12; ++t) {
            const int q = p + 4 * t;               // q covers channels 2q, 2q+1
            float v0, v1;
            if (q < 39) {
                float2 t2 = *(const float2*)(src + 2 * q);
                v0 = t2.x; v1 = t2.y;
            } else if (q == 39) { v0 = latT[2 * hh]; v1 = latT[2 * hh + 1]; }
            else if (q == 40)   { v0 = lonT[2 * ww]; v1 = lonT[2 * ww + 1]; }
            else                { v0 = 0.f; v1 = 0.f; }   // ch 82..95: folded / pad
            xrow[q] = ((unsigned int)f2bf(v1) << 16) | (unsigned int)f2bf(v0);
        }
    }

    // per-column params (overlap with gather latency)
    float b1v[4], lsv[4], lov[4], b2v[4];
    #pragma unroll
    for (int nf = 0; nf < 4; ++nf) {
        int col = wbase + nf * 16 + l15;
        b1v[nf] = b1p[col]; lsv[nf] = lnS[col]; lov[nf] = lnO[col]; b2v[nf] = b2[col];
    }
    __syncthreads();

    // ---- GEMM1: x[64x96] @ W1'[96x256] ----
    f32x4 acc[4][4];
    #pragma unroll
    for (int mf = 0; mf < 4; ++mf)
        #pragma unroll
        for (int nf = 0; nf < 4; ++nf) acc[mf][nf] = (f32x4){0.f, 0.f, 0.f, 0.f};

    #pragma unroll
    for (int s = 0; s < 3; ++s) {
        bf16x8 af[4], bw[4];
        #pragma unroll
        for (int mf = 0; mf < 4; ++mf)
            af[mf] = *(const bf16x8*)&x_lds[mf * 16 + l15][s * 32 + lg * 8];
        #pragma unroll
        for (int nf = 0; nf < 4; ++nf)
            bw[nf] = *(const bf16x8*)(bp1 + ((size_t)((s * 4 + lg) * 256) + wbase + nf * 16 + l15) * 8);
        #pragma unroll
        for (int mf = 0; mf < 4; ++mf)
            #pragma unroll
            for (int nf = 0; nf < 4; ++nf)
                acc[mf][nf] = __builtin_amdgcn_mfma_f32_16x16x32_bf16(af[mf], bw[nf], acc[mf][nf], 0, 0, 0);
    }

    // ---- bias + ReLU + LN partials ----
    float sm[4][4], sq[4][4];
    #pragma unroll
    for (int mf = 0; mf < 4; ++mf)
        #pragma unroll
        for (int i = 0; i < 4; ++i) { sm[mf][i] = 0.f; sq[mf][i] = 0.f; }

    #pragma unroll
    for (int mf = 0; mf < 4; ++mf)
        #pragma unroll
        for (int nf = 0; nf < 4; ++nf)
            #pragma unroll
            for (int i = 0; i < 4; ++i) {
                float v = fmaxf(acc[mf][nf][i] + b1v[nf], 0.f);
                acc[mf][nf][i] = v;
                sm[mf][i] += v;
                sq[mf][i] += v * v;
            }

    #pragma unroll
    for (int m = 1; m < 16; m <<= 1)
        #pragma unroll
        for (int mf = 0; mf < 4; ++mf)
            #pragma unroll
            for (int i = 0; i < 4; ++i) {
                sm[mf][i] += __shfl_xor(sm[mf][i], m, 64);
                sq[mf][i] += __shfl_xor(sq[mf][i], m, 64);
            }

    if (l15 == 0) {
        #pragma unroll
        for (int mf = 0; mf < 4; ++mf)
            #pragma unroll
            for (int i = 0; i < 4; ++i) {
                int row = mf * 16 + lg * 4 + i;
                red[0][wave][row] = sm[mf][i];
                red[1][wave][row] = sq[mf][i];
            }
    }
    __syncthreads();

    // ---- LN finish -> bf16 h_lds (swizzled) ----
    #pragma unroll
    for (int mf = 0; mf < 4; ++mf)
        #pragma unroll
        for (int i = 0; i < 4; ++i) {
            int row = mf * 16 + lg * 4 + i;
            float tot = red[0][0][row] + red[0][1][row] + red[0][2][row] + red[0][3][row];
            float tq  = red[1][0][row] + red[1][1][row] + red[1][2][row] + red[1][3][row];
            float mean = tot * (1.f / 256.f);
            float var  = tq * (1.f / 256.f) - mean * mean;
            float rs = rsqrtf(var + 1e-5f);
            #pragma unroll
            for (int nf = 0; nf < 4; ++nf) {
                float v = (acc[mf][nf][i] - mean) * rs * lsv[nf] + lov[nf];
                int col = wbase + nf * 16 + l15;
                unsigned off = (unsigned)(row * 512 + col * 2);
                off ^= (unsigned)((row & 7) << 4);
                *(unsigned short*)((char*)h_lds + off) = f2bf(v);
            }
        }
    __syncthreads();

    // ---- GEMM2: h[64x256] @ W2[256x256] ----
    #pragma unroll
    for (int mf = 0; mf < 4; ++mf)
        #pragma unroll
        for (int nf = 0; nf < 4; ++nf) acc[mf][nf] = (f32x4){0.f, 0.f, 0.f, 0.f};

    #pragma unroll
    for (int s = 0; s < 8; ++s) {
        bf16x8 af[4], bw[4];
        #pragma unroll
        for (int mf = 0; mf < 4; ++mf) {
            int row = mf * 16 + l15;
            unsigned off = (unsigned)(row * 512 + (s * 32 + lg * 8) * 2);
            off ^= (unsigned)((row & 7) << 4);
            af[mf] = *(const bf16x8*)((char*)h_lds + off);
        }
        #pragma unroll
        for (int nf = 0; nf < 4; ++nf)
            bw[nf] = *(const bf16x8*)(bp2 + ((size_t)((s * 4 + lg) * 256) + wbase + nf * 16 + l15) * 8);
        #pragma unroll
        for (int mf = 0; mf < 4; ++mf)
            #pragma unroll
            for (int nf = 0; nf < 4; ++nf)
                acc[mf][nf] = __builtin_amdgcn_mfma_f32_16x16x32_bf16(af[mf], bw[nf], acc[mf][nf], 0, 0, 0);
    }

    // ---- epilogue: + b2, nontemporal f32 stores (no L2 allocate: stop
    // partial-line eviction write-amplification seen at 4 blocks/CU) ----
    #pragma unroll
    for (int mf = 0; mf < 4; ++mf)
        #pragma unroll
        for (int i = 0; i < 4; ++i) {
            long row_g = block0 + mf * 16 + lg * 4 + i;
            float* po = out + row_g * 256 + wbase;
            #pragma unroll
            for (int nf = 0; nf < 4; ++nf)
                __builtin_nontemporal_store(acc[mf][nf][i] + b2v[nf], po + nf * 16 + l15);
        }
}

extern "C" void kernel_launch(void* const* d_in, const int* in_sizes, int n_in,
                              void* d_out, int out_size, void* d_ws, size_t ws_size,
                              hipStream_t stream) {
    const float* var_grid = (const float*)d_in[0];
    const int*   idxs     = (const int*)d_in[1];
    const float* means    = (const float*)d_in[2];
    const float* stds     = (const float*)d_in[3];
    const float* W1       = (const float*)d_in[4];
    const float* b1       = (const float*)d_in[5];
    const float* lnS      = (const float*)d_in[6];
    const float* lnO      = (const float*)d_in[7];
    const float* W2       = (const float*)d_in[8];
    const float* b2       = (const float*)d_in[9];
    float* out = (float*)d_out;

    char* ws = (char*)d_ws;
    unsigned short* bp1 = (unsigned short*)ws;               // 49152 B
    unsigned short* bp2 = (unsigned short*)(ws + 49152);     // 131072 B -> 180224
    float* latT = (float*)(ws + 180224);                     // 5768 B
    float* lonT = (float*)(ws + 186000);                     // 11520 B
    float* b1p  = (float*)(ws + 197520);                     // 1024 B  (end 198544)

    prep_kernel<<<362, 256, 0, stream>>>(W1, W2, means, stds, b1, bp1, bp2, latT, lonT, b1p);
    fused_kernel<<<NBLOCKS, 256, 0, stream>>>(var_grid, idxs, bp1, bp2, latT, lonT,
                                              b1p, lnS, lnO, b2, out);
}

// Round 4
// 484.868 us; speedup vs baseline: 1.1638x; 1.1496x over previous
//
#include <hip/hip_runtime.h>
#include <hip/hip_bf16.h>
#include <math.h>

#define GH 721
#define GW 1440
#define C_IN 78
#define NNODES 5882
#define KNEIGH 128
#define M_TOTAL (NNODES * KNEIGH)   // 752896
#define TM 64
#define NBLOCKS (M_TOTAL / TM)      // 11764

typedef __attribute__((ext_vector_type(8))) short bf16x8;
typedef __attribute__((ext_vector_type(4))) float f32x4;

__device__ __forceinline__ unsigned short f2bf(float x) {
    __hip_bfloat16 b = __float2bfloat16(x);
    union { __hip_bfloat16 h; unsigned short u; } cv; cv.h = b; return cv.u;
}

// ---------------- prep kernel ----------------
// bp1: [3][4][256][8] bf16 = W1 * inv_std (rows >=82 zero; constants folded into b1p)
// bp2: [8][4][256][8] bf16 = W2
// latT: [721][2] raw (sin,cos) lat;  lonT: [1440][2] raw (sin,cos) lon
// b1p: [256] f32 = b1 - sum_k mean[k]*W1'[k,c] + 0.5*W1'[82,c]
__global__ void prep_kernel(const float* __restrict__ W1, const float* __restrict__ W2,
                            const float* __restrict__ means, const float* __restrict__ stds,
                            const float* __restrict__ b1,
                            unsigned short* __restrict__ bp1, unsigned short* __restrict__ bp2,
                            float* __restrict__ latT, float* __restrict__ lonT,
                            float* __restrict__ b1p)
{
    const int NB1 = 3 * 4 * 256 * 8;   // 24576
    const int NB2 = 8 * 4 * 256 * 8;   // 65536
    const int NTOT = NB1 + NB2 + GH + GW + 256;
    for (int e = blockIdx.x * blockDim.x + threadIdx.x; e < NTOT;
         e += gridDim.x * blockDim.x) {
        if (e < NB1) {
            int j = e & 7, c = (e >> 3) & 255, o = (e >> 11) & 3, s = e >> 13;
            int k = s * 32 + o * 8 + j;
            float v = 0.f;
            if (k < 82) v = W1[k * 256 + c] / (stds[k] + 1e-7f);
            bp1[e] = f2bf(v);
        } else if (e < NB1 + NB2) {
            int t = e - NB1;
            int j = t & 7, c = (t >> 3) & 255, o = (t >> 11) & 3, s = t >> 13;
            int k = s * 32 + o * 8 + j;
            bp2[t] = f2bf(W2[k * 256 + c]);
        } else if (e < NB1 + NB2 + GH) {
            int h = e - NB1 - NB2;
            float r = (-90.f + 0.25f * (float)h) * 0.017453292519943295f;
            latT[2 * h]     = sinf(r);
            latT[2 * h + 1] = cosf(r);
        } else if (e < NB1 + NB2 + GH + GW) {
            int w = e - NB1 - NB2 - GH;
            float r = ((float)w * (360.f / 1439.f)) * 0.017453292519943295f;
            lonT[2 * w]     = sinf(r);
            lonT[2 * w + 1] = cosf(r);
        } else {
            int c = e - NB1 - NB2 - GH - GW;
            float acc = b1[c];
            #pragma unroll 1
            for (int k = 0; k < 86; ++k) {
                float inv = 1.f / (stds[k] + 1e-7f);
                float w = W1[k * 256 + c] * inv;
                acc -= means[k] * w;
                if (k == 82) acc += 0.5f * w;   // day-of-year channel, raw value 0.5
            }
            b1p[c] = acc;
        }
    }
}

// ---------------- fused kernel ----------------
__global__ __launch_bounds__(256, 4)
void fused_kernel(const float* __restrict__ var_grid, const int* __restrict__ idxs,
                  const unsigned short* __restrict__ bp1, const unsigned short* __restrict__ bp2,
                  const float* __restrict__ latT, const float* __restrict__ lonT,
                  const float* __restrict__ b1p, const float* __restrict__ lnS,
                  const float* __restrict__ lnO, const float* __restrict__ b2,
                  float* __restrict__ out)
{
    __shared__ __align__(16) char smem[TM * 256 * 2];   // 32 KiB, three aliases:
    __shared__ float red[2][4][TM];                     // 2 KiB LN partials
    unsigned short* h_lds = (unsigned short*)smem;                    // hidden bf16 (swizzled)
    unsigned short (*x_lds)[104] = (unsigned short (*)[104])smem;     // gathered inputs
    float* otile = (float*)smem;                                      // [32][256] f32 out stage

    const int tid  = threadIdx.x;
    const int lane = tid & 63;
    const int wave = tid >> 6;       // 0..3
    const int l15  = lane & 15;
    const int lg   = lane >> 4;      // 0..3
    const int wbase = wave * 64;
    const long block0 = (long)blockIdx.x * TM;

    // ---- gather: raw values -> bf16 LDS tile (norm folded into W1/b1) ----
    {
        const int row = tid >> 2, p = tid & 3;     // 4 lanes per row
        const int idx = idxs[block0 + row];
        const int hh = idx / GW;
        const int ww = idx - hh * GW;
        const float* src = var_grid + (long)idx * C_IN;
        unsigned int* xrow = (unsigned int*)&x_lds[row][0];
        #pragma unroll
        for (int t = 0; t < 12; ++t) {
            const int q = p + 4 * t;               // q covers channels 2q, 2q+1
            float v0, v1;
            if (q < 39) {
                float2 t2 = *(const float2*)(src + 2 * q);
                v0 = t2.x; v1 = t2.y;
            } else if (q == 39) { v0 = latT[2 * hh]; v1 = latT[2 * hh + 1]; }
            else if (q == 40)   { v0 = lonT[2 * ww]; v1 = lonT[2 * ww + 1]; }
            else                { v0 = 0.f; v1 = 0.f; }   // ch 82..95: folded / pad
            xrow[q] = ((unsigned int)f2bf(v1) << 16) | (unsigned int)f2bf(v0);
        }
    }

    // per-column params (overlap with gather latency)
    float b1v[4], lsv[4], lov[4], b2v[4];
    #pragma unroll
    for (int nf = 0; nf < 4; ++nf) {
        int col = wbase + nf * 16 + l15;
        b1v[nf] = b1p[col]; lsv[nf] = lnS[col]; lov[nf] = lnO[col]; b2v[nf] = b2[col];
    }
    __syncthreads();

    // ---- GEMM1: x[64x96] @ W1'[96x256] ----
    f32x4 acc[4][4];
    #pragma unroll
    for (int mf = 0; mf < 4; ++mf)
        #pragma unroll
        for (int nf = 0; nf < 4; ++nf) acc[mf][nf] = (f32x4){0.f, 0.f, 0.f, 0.f};

    #pragma unroll
    for (int s = 0; s < 3; ++s) {
        bf16x8 af[4], bw[4];
        #pragma unroll
        for (int mf = 0; mf < 4; ++mf)
            af[mf] = *(const bf16x8*)&x_lds[mf * 16 + l15][s * 32 + lg * 8];
        #pragma unroll
        for (int nf = 0; nf < 4; ++nf)
            bw[nf] = *(const bf16x8*)(bp1 + ((size_t)((s * 4 + lg) * 256) + wbase + nf * 16 + l15) * 8);
        #pragma unroll
        for (int mf = 0; mf < 4; ++mf)
            #pragma unroll
            for (int nf = 0; nf < 4; ++nf)
                acc[mf][nf] = __builtin_amdgcn_mfma_f32_16x16x32_bf16(af[mf], bw[nf], acc[mf][nf], 0, 0, 0);
    }

    // ---- bias + ReLU + LN partials ----
    float sm[4][4], sq[4][4];
    #pragma unroll
    for (int mf = 0; mf < 4; ++mf)
        #pragma unroll
        for (int i = 0; i < 4; ++i) { sm[mf][i] = 0.f; sq[mf][i] = 0.f; }

    #pragma unroll
    for (int mf = 0; mf < 4; ++mf)
        #pragma unroll
        for (int nf = 0; nf < 4; ++nf)
            #pragma unroll
            for (int i = 0; i < 4; ++i) {
                float v = fmaxf(acc[mf][nf][i] + b1v[nf], 0.f);
                acc[mf][nf][i] = v;
                sm[mf][i] += v;
                sq[mf][i] += v * v;
            }

    #pragma unroll
    for (int m = 1; m < 16; m <<= 1)
        #pragma unroll
        for (int mf = 0; mf < 4; ++mf)
            #pragma unroll
            for (int i = 0; i < 4; ++i) {
                sm[mf][i] += __shfl_xor(sm[mf][i], m, 64);
                sq[mf][i] += __shfl_xor(sq[mf][i], m, 64);
            }

    if (l15 == 0) {
        #pragma unroll
        for (int mf = 0; mf < 4; ++mf)
            #pragma unroll
            for (int i = 0; i < 4; ++i) {
                int row = mf * 16 + lg * 4 + i;
                red[0][wave][row] = sm[mf][i];
                red[1][wave][row] = sq[mf][i];
            }
    }
    __syncthreads();

    // ---- LN finish -> bf16 h_lds (swizzled) ----
    #pragma unroll
    for (int mf = 0; mf < 4; ++mf)
        #pragma unroll
        for (int i = 0; i < 4; ++i) {
            int row = mf * 16 + lg * 4 + i;
            float tot = red[0][0][row] + red[0][1][row] + red[0][2][row] + red[0][3][row];
            float tq  = red[1][0][row] + red[1][1][row] + red[1][2][row] + red[1][3][row];
            float mean = tot * (1.f / 256.f);
            float var  = tq * (1.f / 256.f) - mean * mean;
            float rs = rsqrtf(var + 1e-5f);
            #pragma unroll
            for (int nf = 0; nf < 4; ++nf) {
                float v = (acc[mf][nf][i] - mean) * rs * lsv[nf] + lov[nf];
                int col = wbase + nf * 16 + l15;
                unsigned off = (unsigned)(row * 512 + col * 2);
                off ^= (unsigned)((row & 7) << 4);
                *(unsigned short*)((char*)h_lds + off) = f2bf(v);
            }
        }
    __syncthreads();

    // ---- GEMM2: h[64x256] @ W2[256x256] ----
    #pragma unroll
    for (int mf = 0; mf < 4; ++mf)
        #pragma unroll
        for (int nf = 0; nf < 4; ++nf) acc[mf][nf] = (f32x4){0.f, 0.f, 0.f, 0.f};

    #pragma unroll
    for (int s = 0; s < 8; ++s) {
        bf16x8 af[4], bw[4];
        #pragma unroll
        for (int mf = 0; mf < 4; ++mf) {
            int row = mf * 16 + l15;
            unsigned off = (unsigned)(row * 512 + (s * 32 + lg * 8) * 2);
            off ^= (unsigned)((row & 7) << 4);
            af[mf] = *(const bf16x8*)((char*)h_lds + off);
        }
        #pragma unroll
        for (int nf = 0; nf < 4; ++nf)
            bw[nf] = *(const bf16x8*)(bp2 + ((size_t)((s * 4 + lg) * 256) + wbase + nf * 16 + l15) * 8);
        #pragma unroll
        for (int mf = 0; mf < 4; ++mf)
            #pragma unroll
            for (int nf = 0; nf < 4; ++nf)
                acc[mf][nf] = __builtin_amdgcn_mfma_f32_16x16x32_bf16(af[mf], bw[nf], acc[mf][nf], 0, 0, 0);
    }

    // ---- epilogue: stage 32-row f32 tiles in LDS, store whole 1-KB rows ----
    // Every store instruction = 64 lanes x 16 B contiguous = 8 full 128-B lines:
    // kills the partial-line fill (FETCH +0.5x out) and line-evict (WRITE 2x out)
    // amplification seen at 4 blocks/CU with 64-B quarter-wave stores.
    #pragma unroll
    for (int p = 0; p < 2; ++p) {
        __syncthreads();   // p=0: GEMM2 LDS reads done; p=1: prev phase reads done
        #pragma unroll
        for (int mfl = 0; mfl < 2; ++mfl) {
            const int mf = p * 2 + mfl;
            #pragma unroll
            for (int i = 0; i < 4; ++i) {
                int rl = mfl * 16 + lg * 4 + i;     // 0..31
                #pragma unroll
                for (int nf = 0; nf < 4; ++nf)
                    otile[rl * 256 + wbase + nf * 16 + l15] = acc[mf][nf][i] + b2v[nf];
            }
        }
        __syncthreads();
        #pragma unroll
        for (int r8 = 0; r8 < 8; ++r8) {
            const int rl = wave * 8 + r8;           // 0..31
            const long row_g = block0 + p * 32 + rl;
            f32x4 v = *(const f32x4*)&otile[rl * 256 + lane * 4];
            __builtin_nontemporal_store(v, (f32x4*)(out + row_g * 256 + lane * 4));
        }
    }
}

extern "C" void kernel_launch(void* const* d_in, const int* in_sizes, int n_in,
                              void* d_out, int out_size, void* d_ws, size_t ws_size,
                              hipStream_t stream) {
    const float* var_grid = (const float*)d_in[0];
    const int*   idxs     = (const int*)d_in[1];
    const float* means    = (const float*)d_in[2];
    const float* stds     = (const float*)d_in[3];
    const float* W1       = (const float*)d_in[4];
    const float* b1       = (const float*)d_in[5];
    const float* lnS      = (const float*)d_in[6];
    const float* lnO      = (const float*)d_in[7];
    const float* W2       = (const float*)d_in[8];
    const float* b2       = (const float*)d_in[9];
    float* out = (float*)d_out;

    char* ws = (char*)d_ws;
    unsigned short* bp1 = (unsigned short*)ws;               // 49152 B
    unsigned short* bp2 = (unsigned short*)(ws + 49152);     // 131072 B -> 180224
    float* latT = (float*)(ws + 180224);                     // 5768 B
    float* lonT = (float*)(ws + 186000);                     // 11520 B
    float* b1p  = (float*)(ws + 197520);                     // 1024 B  (end 198544)

    prep_kernel<<<362, 256, 0, stream>>>(W1, W2, means, stds, b1, bp1, bp2, latT, lonT, b1p);
    fused_kernel<<<NBLOCKS, 256, 0, stream>>>(var_grid, idxs, bp1, bp2, latT, lonT,
                                              b1p, lnS, lnO, b2, out);
}